// Round 5
// baseline (105.080 us; speedup 1.0000x reference)
//
#include <hip/hip_runtime.h>

// Problem constants (fixed by reference setup_inputs)
#define BATCH 8
#define NPTS  4096   // N == M == 4096
#define KD    64
#define MQ    4      // m-strips: each block walks 1024 cols = 8 tiles of 128
#define WALK  8
#define FINF  3.0e38f

typedef float f32x4 __attribute__((ext_vector_type(4)));
typedef float f32x2 __attribute__((ext_vector_type(2)));
typedef short s16x8 __attribute__((ext_vector_type(8)));

__device__ __forceinline__ unsigned int f2bf(float f) {
  // round-to-nearest-even fp32 -> bf16 (inputs finite)
  unsigned int u = __float_as_uint(f);
  u += 0x7FFFu + ((u >> 16) & 1u);
  return u >> 16;
}

__device__ __forceinline__ void stage16(const void* g, void* l) {
  // async global->LDS, 16B/lane; LDS dst = wave-uniform base + lane*16
  __builtin_amdgcn_global_load_lds((const __attribute__((address_space(1))) void*)g,
                                   (__attribute__((address_space(3))) void*)l, 16, 0, 0);
}

// ---------------------------------------------------------------------------
// Prepass: convert X,Y (fp32 [32768][64]) to bf16 packed (uint [32768][32])
// and compute exact fp32 squared norms. 32 threads per row, 2 floats/thread.
// Also zeroes the reduce-phase counter and +inf-inits the rowmin/colmin
// atomic buffers (re-poisoned by the harness each iteration; stream order
// makes this race-free).
__global__ __launch_bounds__(256)
void prep_kernel(const float* __restrict__ X, const float* __restrict__ Y,
                 unsigned int* __restrict__ Xbf, unsigned int* __restrict__ Ybf,
                 float* __restrict__ x2, float* __restrict__ y2,
                 unsigned int* __restrict__ minbuf,   // rowmin[32K] | colmin[32K]
                 unsigned int* __restrict__ counter) {
  int gid = blockIdx.x * 256 + threadIdx.x;
  if (gid == 0) *counter = 0;
  if (gid < 2 * BATCH * NPTS) minbuf[gid] = 0x7F800000u;  // +inf (uint-ordered)
  int row = gid >> 5;
  int ki  = gid & 31;
  bool isX = row < BATCH * NPTS;
  int r2 = row & (BATCH * NPTS - 1);
  const float* src = isX ? X : Y;
  f32x2 v = *(const f32x2*)(src + (size_t)r2 * KD + ki * 2);
  float s = v[0] * v[0] + v[1] * v[1];
  #pragma unroll
  for (int m = 16; m >= 1; m >>= 1) s += __shfl_xor(s, m, 64);  // stays in 32-lane half
  unsigned int packed = (f2bf(v[1]) << 16) | f2bf(v[0]);
  (isX ? Xbf : Ybf)[r2 * 32 + ki] = packed;
  if (ki == 0) (isX ? x2 : y2)[r2] = s;
}

// ---------------------------------------------------------------------------
// Main: 1024 blocks, 1D grid with XCD<->batch affinity swizzle: hardware
// block id `lin` round-robins XCDs by lin&7 [m09], and the remap
// logical = (lin&7)*128 + (lin>>3) makes b = logical>>7 = lin&7 — so every
// block of batch b runs on XCD b, and that batch's whole bf16 working set
// (Xbf+Ybf = 1MB + norms) lives in ONE private 4MB L2. All X/Y strip
// re-reads (~18MB/XCD) become same-XCD L2 hits instead of LLC traffic.
// Block work: 128 rows x 1024 cols (8 m-tiles of 128), waves 2x2, wave tile
// 64x64. X fragments gathered straight from global (L2-hot, read once per
// block); LDS = Y double-buffer 32KB + credq/redf ~5KB -> 4 blocks/CU.
// Min-partials go out via clamped uint atomicMin (exact: float-as-uint
// ordering is monotone for non-negative floats, and clamping before the min
// equals the reference's max(sq,0) since clamp∘min = min∘clamp). With the
// swizzle, all writers of an entry share an XCD -> L2-local atomics.
// tt-loop stays `#pragma unroll 2` (full 8x unroll spilled: 528MB scratch,
// round 2). launch_bounds(256,2): 128 VGPR — exactly the 4-blocks/CU cap.
__global__ __launch_bounds__(256, 2)
void chamfer_main(const unsigned short* __restrict__ Xbf,
                  const unsigned short* __restrict__ Ybf,
                  const float* __restrict__ x2g, const float* __restrict__ y2g,
                  unsigned int* __restrict__ rowmin,   // [B*N] min over cols (sq, clamped)
                  unsigned int* __restrict__ colmin) { // [B*M] min over rows (sq, clamped)
  __shared__ __align__(16) unsigned short Ys[2][128 * 64];   // 32 KB
  __shared__ float l_credq[2 * 4 * 132];                     // 4.1 KB, +4 pad vs banks
  __shared__ float l_redf[256];                              // 1 KB

  const int lin = blockIdx.x;                       // hw id; XCD = lin & 7
  const int logical = (lin & 7) * 128 + (lin >> 3); // bijective (1024 = 8*128)
  const int mq = logical & 3, ntile = (logical >> 2) & 31, b = logical >> 7;
  const int n0 = ntile * 128;
  const int mbase = mq * (WALK * 128);
  const int t = threadIdx.x, w = t >> 6, lane = t & 63, c = lane & 15, q = lane >> 4;
  const int wr = (w >> 1) * 64, wc = (w & 1) * 64, rg = w >> 1;

  // staging source offset within a 1KB (8-row) block: row=lane>>3, chunk=(lane&7)^(lane>>3)
  const int l8 = lane >> 3;
  const int lane_off = l8 * 128 + (((lane & 7) ^ l8) << 4);

  const unsigned short* Xrow = Xbf + (size_t)(b * NPTS + n0) * KD;  // [128][64] bf16
  const char* Yg0 = (const char*)(Ybf + (size_t)(b * NPTS + mbase) * KD);

  // Prologue: stage Y tile 0 (4 x 1KB per wave)
  #pragma unroll
  for (int k = 0; k < 4; ++k)
    stage16(Yg0 + (k * 32 + w * 8) * 128 + lane_off,
            (char*)Ys[0] + (k * 256 + w * 64) * 16);

  // X fragments straight from global (once per block). Lane (q,c) reads rows
  // wr+i*16+c, k-chunk (ks*4+q)*8 — per instr: 16 rows x 64B segments. 32 VGPRs.
  s16x8 xf[4][2];
  #pragma unroll
  for (int i = 0; i < 4; ++i)
    #pragma unroll
    for (int ks = 0; ks < 2; ++ks)
      xf[i][ks] = *(const s16x8*)&Xrow[(size_t)(wr + i * 16 + c) * KD + (ks * 4 + q) * 8];

  // x2 fragment (rows wr + i*16 + q*4 + r), fp32, L2-hot. 16 VGPRs.
  const float* x2b = x2g + b * NPTS + n0;
  f32x4 x2r[4];
  #pragma unroll
  for (int i = 0; i < 4; ++i) x2r[i] = *(const f32x4*)(x2b + wr + i * 16 + q * 4);

  __syncthreads();  // drains the Y0 global_load_lds (vmcnt 0 at barrier)

  float rm[4][4];
  #pragma unroll
  for (int i = 0; i < 4; ++i)
    #pragma unroll
    for (int r = 0; r < 4; ++r) rm[i][r] = FINF;

  const int cx = c & 7;
  const float* y2b = y2g + b * NPTS + mbase;
  unsigned int* colbase = colmin + (size_t)b * NPTS + mbase;
  const f32x4 zacc = {0.f, 0.f, 0.f, 0.f};

  #pragma unroll 2
  for (int tt = 0; tt < WALK; ++tt) {
    const unsigned short* cur = Ys[tt & 1];

    // y2 for this wave's 4 col groups — issue global loads first (async).
    float y2c[4];
    #pragma unroll
    for (int j = 0; j < 4; ++j) y2c[j] = y2b[tt * 128 + wc + j * 16 + c];

    if (tt < WALK - 1) {  // async-prefetch next Y tile into the other buffer
      const char* Ygt = Yg0 + (size_t)(tt + 1) * 128 * 128;
      unsigned short* nb = Ys[(tt + 1) & 1];
      #pragma unroll
      for (int k = 0; k < 4; ++k)
        stage16(Ygt + (k * 32 + w * 8) * 128 + lane_off,
                (char*)nb + (k * 256 + w * 64) * 16);
    }

    // Flush previous tile's col-mins: combine 4 q-pair/rowgroup partials,
    // add y2, clamp, atomicMin (L2-local: all writers share XCD b).
    // l_credq[pb] was written before the barrier that ended tt-1 -> visible;
    // it is rewritten only after the barrier ending THIS tt.
    if (tt > 0 && t < 128) {
      int pt = tt - 1, pb = pt & 1;
      float v = fminf(fminf(l_credq[(pb * 4 + 0) * 132 + t], l_credq[(pb * 4 + 1) * 132 + t]),
                      fminf(l_credq[(pb * 4 + 2) * 132 + t], l_credq[(pb * 4 + 3) * 132 + t]));
      float d = fmaxf(v + y2b[pt * 128 + t], 0.f);
      atomicMin(&colbase[pt * 128 + t], __float_as_uint(d));
    }

    float cmj[4];
    #pragma unroll
    for (int j = 0; j < 4; ++j) {
      const unsigned short* yrow = &cur[(wc + j * 16 + c) * 64];
      s16x8 yf0 = *(const s16x8*)&yrow[(q ^ cx) << 3];
      s16x8 yf1 = *(const s16x8*)&yrow[((4 + q) ^ cx) << 3];
      f32x4 acc[4];
      #pragma unroll
      for (int i = 0; i < 4; ++i) {
        f32x4 a0 = __builtin_amdgcn_mfma_f32_16x16x32_bf16(xf[i][0], yf0, zacc, 0, 0, 0);
        acc[i] = __builtin_amdgcn_mfma_f32_16x16x32_bf16(xf[i][1], yf1, a0, 0, 0, 0);
      }
      float cm = FINF;
      #pragma unroll
      for (int i = 0; i < 4; ++i)
        #pragma unroll
        for (int r = 0; r < 4; ++r) {
          float v = acc[i][r];
          rm[i][r] = fminf(rm[i][r], fmaf(-2.f, v, y2c[j]));
          cm = fminf(cm, fmaf(-2.f, v, x2r[i][r]));
        }
      // ONE cross-lane step: combine q-pairs {0,1} and {2,3}
      cm = fminf(cm, __shfl_xor(cm, 16, 64));
      cmj[j] = cm;
    }
    // Each lane stores 2 of the (q-half, j) partials: q&1 picks the j-pair,
    // q>>1 picks the row-half slot. Addr stride 132 breaks the x128 bank alias.
    {
      int s = rg * 2 + (q >> 1);
      int jA = (q & 1) * 2;
      float sA = (q & 1) ? cmj[2] : cmj[0];
      float sB = (q & 1) ? cmj[3] : cmj[1];
      float* dst = &l_credq[((tt & 1) * 4 + s) * 132 + wc + c];
      dst[jA * 16]      = sA;
      dst[jA * 16 + 16] = sB;
    }

    __syncthreads();  // buffer swap barrier (prefetch had MFMA+epilogue to land)
  }

  // Row-min: reduce over the 16 c-lanes within each q-group...
  #pragma unroll
  for (int msk = 1; msk <= 8; msk <<= 1)
    #pragma unroll
    for (int i = 0; i < 4; ++i)
      #pragma unroll
      for (int r = 0; r < 4; ++r)
        rm[i][r] = fminf(rm[i][r], __shfl_xor(rm[i][r], msk, 64));
  // ...then store per-wave row-mins to LDS (literal indices only).
  if (c == 0) {
    #pragma unroll
    for (int i = 0; i < 4; ++i) {
      f32x4 v = {rm[i][0], rm[i][1], rm[i][2], rm[i][3]};
      *(f32x4*)&l_redf[w * 64 + i * 16 + q * 4] = v;
    }
  }
  __syncthreads();

  if (t < 128) {
    // flush the final tile's col-mins (last loop barrier made them visible)
    {
      int pt = WALK - 1, pb = pt & 1;
      float v = fminf(fminf(l_credq[(pb * 4 + 0) * 132 + t], l_credq[(pb * 4 + 1) * 132 + t]),
                      fminf(l_credq[(pb * 4 + 2) * 132 + t], l_credq[(pb * 4 + 3) * 132 + t]));
      float d = fmaxf(v + y2b[pt * 128 + t], 0.f);
      atomicMin(&colbase[pt * 128 + t], __float_as_uint(d));
    }
    // combine the 2 col-group waves of each row group, add x2, clamp, atomicMin
    int g = t >> 6, lr = t & 63;
    float v = fminf(l_redf[(g * 2) * 64 + lr], l_redf[(g * 2 + 1) * 64 + lr]) + x2b[t];
    atomicMin(&rowmin[(size_t)b * NPTS + n0 + t], __float_as_uint(fmaxf(v, 0.f)));
  }
}

// ---------------------------------------------------------------------------
// Final: sqrt + mean over the prefolded rowmin/colmin (256KB read) —
// self-finalizing via device-scope ticket. 128 blocks.
__global__ __launch_bounds__(256)
void reduce_kernel(const unsigned int* __restrict__ rowmin,
                   const unsigned int* __restrict__ colmin,
                   float* __restrict__ partials, unsigned int* __restrict__ counter,
                   float* __restrict__ out) {
  int i = blockIdx.x * 256 + threadIdx.x;
  const int TOT = BATCH * NPTS;
  // entries are clamped >=0 by the writers; every entry written by >=1 block
  float s0 = sqrtf(__uint_as_float(rowmin[i])) + sqrtf(__uint_as_float(colmin[i]));
  #pragma unroll
  for (int m = 32; m >= 1; m >>= 1) s0 += __shfl_xor(s0, m, 64);
  __shared__ float wsum[4];
  if ((threadIdx.x & 63) == 0) wsum[threadIdx.x >> 6] = s0;
  __syncthreads();

  if (threadIdx.x < 64) {  // wave 0 publishes the block partial, then maybe finalizes
    unsigned int ticket = 0;
    if (threadIdx.x == 0) {
      float bsum = wsum[0] + wsum[1] + wsum[2] + wsum[3];
      atomicExch(&partials[blockIdx.x], bsum);  // device-scope visible store
      __threadfence();
      ticket = atomicAdd(counter, 1);
    }
    ticket = __shfl(ticket, 0, 64);
    if (ticket == 127) {  // all 128 partials published
      float v = atomicAdd(&partials[threadIdx.x], 0.0f) +
                atomicAdd(&partials[threadIdx.x + 64], 0.0f);
      #pragma unroll
      for (int m = 32; m >= 1; m >>= 1) v += __shfl_xor(v, m, 64);
      if (threadIdx.x == 0) out[0] = v * (1.0f / (float)TOT);
    }
  }
}

// ---------------------------------------------------------------------------
extern "C" void kernel_launch(void* const* d_in, const int* in_sizes, int n_in,
                              void* d_out, int out_size, void* d_ws, size_t ws_size,
                              hipStream_t stream) {
  const float* X = (const float*)d_in[0];  // [B, N, 64] fp32
  const float* Y = (const float*)d_in[1];  // [B, M, 64] fp32
  float* out = (float*)d_out;

  // Workspace layout (bytes):
  //   Xbf 4MB | Ybf 4MB | x2 128KB | y2 128KB | rowmin 128KB | colmin 128KB
  //   | partials 512B | counter 4B
  char* ws = (char*)d_ws;
  unsigned int* Xbf = (unsigned int*)ws;                       // packed bf16 pairs
  unsigned int* Ybf = (unsigned int*)(ws + (4u << 20));
  float* x2 = (float*)(ws + (8u << 20));
  float* y2 = (float*)(ws + (8u << 20) + (128u << 10));
  unsigned int* minbuf = (unsigned int*)(ws + (8u << 20) + (256u << 10));
  unsigned int* rowmin = minbuf;                               // [32768]
  unsigned int* colmin = minbuf + BATCH * NPTS;                // [32768]
  float* partials = (float*)(ws + (8u << 20) + (512u << 10));
  unsigned int* counter = (unsigned int*)(partials + 128);

  // Prepass: both inputs, 32 threads/row. Also zeroes `counter` and
  // +inf-inits rowmin/colmin.
  prep_kernel<<<dim3(2 * BATCH * NPTS * 32 / 256), dim3(256), 0, stream>>>(
      X, Y, Xbf, Ybf, x2, y2, minbuf, counter);

  // Main: 1024 blocks 1D (XCD swizzle decoded in-kernel), 4 resident/CU.
  chamfer_main<<<dim3(MQ * 32 * BATCH), dim3(256), 0, stream>>>(
      (const unsigned short*)Xbf, (const unsigned short*)Ybf, x2, y2, rowmin, colmin);

  // Final sqrt/mean over prefolded mins (self-finalizing via ticket).
  reduce_kernel<<<dim3(BATCH * NPTS / 256), dim3(256), 0, stream>>>(
      rowmin, colmin, partials, counter, out);
}